// Round 1
// 195.710 us; speedup vs baseline: 1.0417x; 1.0417x over previous
//
#include <hip/hip_runtime.h>
#include <hip/hip_bf16.h>

// Problem: B=8, T=1024, C=768, H=12, HD=64. M = 8192. fp32 in/out.
// R14: qkv GEMM rewritten as the 256x256 8-phase schedule (T2 XOR-swizzle +
// T3/T4 counted vmcnt(6) + T5 setprio). 12 K-tiles of BK=64, 2 tiles/iter,
// consumption-aligned half-tile staging, B0 frags held in regs p1->p4.
// Grid 288 blocks (32x9), XCD-swizzled. Epilogue (V-transposed stores, Q/K
// per-wave LDS transpose) unchanged in logic; scratch reuses main LDS after
// vmcnt(0)+barrier. attn (R12) + proj + casts unchanged.

#define TDIM 1024
#define CDIM 768
#define NDIM 2304

typedef __attribute__((ext_vector_type(8))) short bf16x8;
typedef __attribute__((ext_vector_type(8))) unsigned short u16x8;
typedef __attribute__((ext_vector_type(4))) float f32x4;

__device__ __forceinline__ unsigned short f2bf(float f) {
    unsigned int u;
    __builtin_memcpy(&u, &f, 4);
    u += 0x7FFFu + ((u >> 16) & 1u);  // RNE
    return (unsigned short)(u >> 16);
}

__device__ __forceinline__ void async_copy16(void* lds, const void* g) {
    __builtin_amdgcn_global_load_lds(
        (const __attribute__((address_space(1))) void*)g,
        (__attribute__((address_space(3))) void*)lds, 16, 0, 0);
}

// ---------------------------------------------------------------------------
// Precast kernels.
// ---------------------------------------------------------------------------
__global__ __launch_bounds__(256) void cast_x(const float* __restrict__ x,
                                              unsigned short* __restrict__ xb) {
    const size_t i = ((size_t)blockIdx.x * 256 + threadIdx.x) * 4;
    float4 v = *(const float4*)&x[i];
    ushort4 s;
    s.x = f2bf(v.x); s.y = f2bf(v.y); s.z = f2bf(v.z); s.w = f2bf(v.w);
    *(ushort4*)&xb[i] = s;
}

template <int N>
__global__ __launch_bounds__(256) void transpose_cast(const float* __restrict__ W,
                                                      unsigned short* __restrict__ Wt) {
    __shared__ float tile[32][33];
    const int n0 = blockIdx.x * 32;
    const int k0 = blockIdx.y * 32;
    const int tx = threadIdx.x & 31;
    const int ty = threadIdx.x >> 5;
#pragma unroll
    for (int i = 0; i < 4; ++i)
        tile[ty + i * 8][tx] = W[(size_t)(k0 + ty + i * 8) * N + n0 + tx];
    __syncthreads();
#pragma unroll
    for (int i = 0; i < 4; ++i)
        Wt[(size_t)(n0 + ty + i * 8) * CDIM + k0 + tx] = f2bf(tile[tx][ty + i * 8]);
}

// ---------------------------------------------------------------------------
// Kernel 1: qkv GEMM — 256x256 tile, BK=64, 8 waves (2M x 4N), 8-phase
// schedule with double-buffered LDS and counted vmcnt.
//
// LDS: buf p in {0,1}: A[p] = lds[p*32768 .. +16384), B[p] = +16384.
// Layout [256 rows][8 chunks of 16B], chunk swizzle c' = c ^ (row & 7).
// global_load_lds writes linearly (wave-uniform base + lane*16), so the
// source global address is pre-swizzled and ds_read applies the same XOR.
//
// Half-tiles are consumption-aligned:
//   A-half mh = rows {wm*128 + mh*64 + [0,64)}  (LDS-dead after its quadrant
//   pair's first phase), B-half nh = rows {wn*64 + nh*32 + [0,32)}.
// Quadrant order per tile: (0,0),(0,1),(1,1),(1,0); B0 frags stay in regs
// p1->p4 so B-half0 is LDS-dead after p1.
// Stage schedule (steady state): p1:A1(t1)->b1, p2:A0(t2)->b0, p3:B0(t2),
// p4:B1(t2), p5:A1(t2), p6:A0(t3)->b1, p7:B0(t3), p8:B1(t3).
// vmcnt(6) at p4/p8 only (2 loads/thread/half-tile, 3 half-tiles in flight).
// ---------------------------------------------------------------------------
__global__ __launch_bounds__(512, 2) void qkv_mfma(
    const unsigned short* __restrict__ xb, const unsigned short* __restrict__ Wt,
    const float* __restrict__ bias,
    unsigned short* __restrict__ Q, unsigned short* __restrict__ Kd,
    unsigned short* __restrict__ Vt)
{
    // XCD-aware swizzle: 288 blocks, 288 % 8 == 0 -> bijective.
    const int wg = ((int)blockIdx.x & 7) * 36 + ((int)blockIdx.x >> 3);
    const int bx = wg % 9;
    const int by = wg / 9;
    const int n0 = bx * 256;
    const int m0 = by * 256;
    const int tid = threadIdx.x;
    const int lane = tid & 63;
    const int w = tid >> 6;
    const int wm = w >> 2;   // 0..1
    const int wn = w & 3;    // 0..3
    const int lm = lane & 15;
    const int lq = lane >> 4;

    __shared__ __align__(16) unsigned short lds[65536];  // 128 KiB

    // Bias preloaded BEFORE any staging so these vmem loads retire inside the
    // prologue vmcnt and never perturb the in-loop vmcnt(6) accounting.
    float bb[4];
#pragma unroll
    for (int ni = 0; ni < 4; ++ni) bb[ni] = bias[n0 + wn * 64 + ni * 16 + lm];

    f32x4 acc[8][4] = {};
    bf16x8 aF[4][2], bF0[2][2], bF1[2][2];

    // ds_read chunk swizzle: logical chunk c = ks*4+lq, row low bits e=lm&7,
    // swizzled chunk = (lq ^ e) ^ (4*ks).
    const int eo = lq ^ (lm & 7);
    const unsigned short* pA[2][2];
    const unsigned short* pB[2][2];
#pragma unroll
    for (int p = 0; p < 2; ++p)
#pragma unroll
        for (int ks = 0; ks < 2; ++ks) {
            pA[p][ks] = &lds[p * 32768 + (wm * 128 + lm) * 64 + (eo ^ (4 * ks)) * 8];
            pB[p][ks] = &lds[p * 32768 + 16384 + (wn * 64 + lm) * 64 + (eo ^ (4 * ks)) * 8];
        }

#define LDA(pp, mh)                                                             \
    _Pragma("unroll")                                                           \
    for (int mi2 = 0; mi2 < 4; ++mi2)                                           \
        _Pragma("unroll")                                                       \
        for (int ks = 0; ks < 2; ++ks)                                          \
            aF[mi2][ks] = *(const bf16x8*)(pA[pp][ks] + ((mh) * 64 + mi2 * 16) * 64)

#define LDB(pp, nh, BF)                                                         \
    _Pragma("unroll")                                                           \
    for (int nj = 0; nj < 2; ++nj)                                              \
        _Pragma("unroll")                                                       \
        for (int ks = 0; ks < 2; ++ks)                                          \
            BF[nj][ks] = *(const bf16x8*)(pB[pp][ks] + ((nh) * 32 + nj * 16) * 64)

#define MM(mh, nh, BF)                                                          \
    _Pragma("unroll")                                                           \
    for (int mi2 = 0; mi2 < 4; ++mi2)                                           \
        _Pragma("unroll")                                                       \
        for (int nj = 0; nj < 2; ++nj)                                          \
            _Pragma("unroll")                                                   \
            for (int ks = 0; ks < 2; ++ks)                                      \
                acc[(mh) * 4 + mi2][(nh) * 2 + nj] =                            \
                    __builtin_amdgcn_mfma_f32_16x16x32_bf16(                    \
                        aF[mi2][ks], BF[nj][ks],                                \
                        acc[(mh) * 4 + mi2][(nh) * 2 + nj], 0, 0, 0)

    // Stage one A half-tile (2 x global_load_lds per thread). LDS dest is
    // linear; the XOR swizzle is applied to the global SOURCE column chunk.
#define STG_A(pp, kt, mh)                                                       \
    do {                                                                        \
        _Pragma("unroll")                                                       \
        for (int j = 0; j < 2; ++j) {                                           \
            const int nbase = w * 128 + j * 64;                                 \
            const int nl = nbase + lane;                                        \
            const int rl = nl >> 3;                                             \
            const int cc = (nl & 7) ^ (rl & 7);                                 \
            const int rowG = (rl & 63) + (mh) * 64 + ((rl >> 6) << 7);          \
            async_copy16(&lds[(pp) * 32768 +                                    \
                              ((mh) * 512 + (nbase & 511) +                     \
                               ((nbase >= 512) ? 1024 : 0)) * 8],               \
                         &xb[(size_t)(m0 + rowG) * CDIM + (kt) * 64 + cc * 8]); \
        }                                                                       \
    } while (0)

#define STG_B(pp, kt, nh)                                                       \
    do {                                                                        \
        _Pragma("unroll")                                                       \
        for (int j = 0; j < 2; ++j) {                                           \
            const int nbase = w * 128 + j * 64;                                 \
            const int nl = nbase + lane;                                        \
            const int rl = nl >> 3;                                             \
            const int cc = (nl & 7) ^ (rl & 7);                                 \
            const int rowG = ((rl >> 5) << 6) + (nh) * 32 + (rl & 31);          \
            async_copy16(&lds[(pp) * 32768 + 16384 +                            \
                              (((nbase >> 8) << 9) + (nh) * 256 +               \
                               (nbase & 255)) * 8],                             \
                         &Wt[(size_t)(n0 + rowG) * CDIM + (kt) * 64 + cc * 8]); \
        }                                                                       \
    } while (0)

#define BAR_MID()                                                               \
    __builtin_amdgcn_s_barrier();                                               \
    asm volatile("s_waitcnt lgkmcnt(0)" ::: "memory");                          \
    __builtin_amdgcn_s_setprio(1)

#define BAR_END()                                                               \
    __builtin_amdgcn_s_setprio(0);                                              \
    __builtin_amdgcn_s_barrier()

#define BAR_END_VM()                                                            \
    __builtin_amdgcn_s_setprio(0);                                              \
    asm volatile("s_waitcnt vmcnt(6)" ::: "memory");                            \
    __builtin_amdgcn_s_barrier()

    // Prologue: t0 fully (A0,B0,B1,A1) + t1 (A0,B0,B1) = 14 loads/thread.
    STG_A(0, 0, 0); STG_B(0, 0, 0); STG_B(0, 0, 1); STG_A(0, 0, 1);
    STG_A(1, 1, 0); STG_B(1, 1, 0); STG_B(1, 1, 1);
    asm volatile("s_waitcnt vmcnt(6)" ::: "memory");  // t0 landed
    __builtin_amdgcn_s_barrier();

#pragma unroll 1
    for (int it = 0; it < 6; ++it) {
        const int t1 = 2 * it + 1;
        const int s2 = (2 * it + 2 < 12) ? (2 * it + 2) : 11;  // clamp: last-iter
        const int s3 = (2 * it + 3 < 12) ? (2 * it + 3) : 11;  // restage = benign
        // ---- tile t0 (buf0) ----
        // p1: Q(0,0)
        LDA(0, 0); LDB(0, 0, bF0);
        STG_A(1, t1, 1);
        BAR_MID(); MM(0, 0, bF0); BAR_END();
        // p2: Q(0,1)
        LDB(0, 1, bF1);
        STG_A(0, s2, 0);
        BAR_MID(); MM(0, 1, bF1); BAR_END();
        // p3: Q(1,1)
        LDA(0, 1);
        STG_B(0, s2, 0);
        BAR_MID(); MM(1, 1, bF1); BAR_END();
        // p4: Q(1,0)  (B0 from regs held since p1)
        STG_B(0, s2, 1);
        BAR_MID(); MM(1, 0, bF0); BAR_END_VM();
        // ---- tile t1 (buf1) ----
        // p5: Q(0,0)
        LDA(1, 0); LDB(1, 0, bF0);
        STG_A(0, s2, 1);
        BAR_MID(); MM(0, 0, bF0); BAR_END();
        // p6: Q(0,1)
        LDB(1, 1, bF1);
        STG_A(1, s3, 0);
        BAR_MID(); MM(0, 1, bF1); BAR_END();
        // p7: Q(1,1)
        LDA(1, 1);
        STG_B(1, s3, 0);
        BAR_MID(); MM(1, 1, bF1); BAR_END();
        // p8: Q(1,0)
        STG_B(1, s3, 1);
        BAR_MID(); MM(1, 0, bF0); BAR_END_VM();
    }

#undef LDA
#undef LDB
#undef MM
#undef STG_A
#undef STG_B
#undef BAR_MID
#undef BAR_END
#undef BAR_END_VM

    // Drain all outstanding DMA before reusing LDS as epilogue scratch.
    asm volatile("s_waitcnt vmcnt(0)" ::: "memory");
    __builtin_amdgcn_s_barrier();

    // Epilogue. Wave's 64-col group: ga = bx*4 + wn; which = ga%3; h = ga/3.
    const int ga = bx * 4 + wn;
    const int which = ga % 3;
    const int h = ga / 3;

    if (which == 2) {
        // V transposed [B,H,D,T]: direct t-contiguous ushort4 stores.
#pragma unroll
        for (int ni = 0; ni < 4; ++ni) {
            const int d = ni * 16 + lm;
#pragma unroll
            for (int mi = 0; mi < 8; ++mi) {
                const int gm0 = m0 + wm * 128 + mi * 16 + lq * 4;
                const int bidx = gm0 >> 10;
                const int t0 = gm0 & 1023;
                ushort4 sv;
                sv.x = f2bf(acc[mi][ni][0] + bb[ni]);
                sv.y = f2bf(acc[mi][ni][1] + bb[ni]);
                sv.z = f2bf(acc[mi][ni][2] + bb[ni]);
                sv.w = f2bf(acc[mi][ni][3] + bb[ni]);
                *(ushort4*)&Vt[(((size_t)bidx * 12 + h) * 64 + d) * TDIM + t0] = sv;
            }
        }
    } else {
        // Q/K [B,H,T,64]: per-wave LDS transpose -> 16B row stores.
        unsigned short* dst = (which == 0) ? Q : Kd;
        unsigned short* Es = &lds[w * 1152];  // 16 x 72 per wave
        const int erow = lane >> 2;   // 0..15
        const int ecol = lane & 3;    // 0..3 -> 16-short chunks
#pragma unroll
        for (int mi = 0; mi < 8; ++mi) {
#pragma unroll
            for (int r = 0; r < 4; ++r)
#pragma unroll
                for (int ni = 0; ni < 4; ++ni)
                    Es[(lq * 4 + r) * 72 + ni * 16 + lm] = f2bf(acc[mi][ni][r] + bb[ni]);
            // same-wave LDS write->read (in-order per wave; validated since R7)
            const int t = m0 + wm * 128 + mi * 16 + erow;
            const int bidx = t >> 10;
            const int tt = t & 1023;
            unsigned short* drow = &dst[(((size_t)bidx * 12 + h) * TDIM + tt) * 64];
            u16x8 v0 = *(const u16x8*)&Es[erow * 72 + ecol * 16];
            u16x8 v1 = *(const u16x8*)&Es[erow * 72 + ecol * 16 + 8];
            *(u16x8*)&drow[ecol * 16] = v0;
            *(u16x8*)&drow[ecol * 16 + 8] = v1;
        }
    }
}

// ---------------------------------------------------------------------------
// Kernel 2: MFMA causal flash attention v4 (R12, verified) — 64-query tiles
// paired (pi, 15-pi); shift-free softmax; V pre-transposed; Q frags direct.
// ---------------------------------------------------------------------------
#define ATTN_TILE(aq, q0t, qt_t, l_p, o) do {                                   \
    const bool diag_ = (kt == (qt_t));                                          \
    float pf[4][4];                                                             \
    _Pragma("unroll")                                                           \
    for (int nt = 0; nt < 4; ++nt) {                                            \
        f32x4 s = {};                                                           \
        _Pragma("unroll")                                                       \
        for (int kc = 0; kc < 2; ++kc) {                                        \
            bf16x8 bfrag = *(const bf16x8*)&Ks[nt * 16 + lm][kc * 32 + lq * 8]; \
            s = __builtin_amdgcn_mfma_f32_16x16x32_bf16(aq[kc], bfrag, s, 0, 0, 0); \
        }                                                                       \
        const int keyg = kbase + nt * 16 + lm;                                  \
        _Pragma("unroll")                                                       \
        for (int r = 0; r < 4; ++r) {                                           \
            float p = __builtin_amdgcn_exp2f(s[r] * SC);                        \
            if (diag_) {                                                        \
                const int qg = (q0t) + w * 16 + lq * 4 + r;                     \
                if (keyg > qg) p = 0.f;                                         \
            }                                                                   \
            pf[nt][r] = p;                                                      \
        }                                                                       \
    }                                                                           \
    _Pragma("unroll")                                                           \
    for (int r = 0; r < 4; ++r) {                                               \
        l_p[r] += pf[0][r] + pf[1][r] + pf[2][r] + pf[3][r];                    \
        _Pragma("unroll")                                                       \
        for (int nt = 0; nt < 4; ++nt)                                          \
            Ps[w][lq * 4 + r][nt * 16 + lm] = f2bf(pf[nt][r]);                  \
    }                                                                           \
    {                                                                           \
        bf16x8 ap[2];                                                           \
        _Pragma("unroll")                                                       \
        for (int kc = 0; kc < 2; ++kc)                                          \
            ap[kc] = *(const bf16x8*)&Ps[w][lm][kc * 32 + lq * 8];              \
        _Pragma("unroll")                                                       \
        for (int nt = 0; nt < 4; ++nt) {                                        \
            _Pragma("unroll")                                                   \
            for (int kc = 0; kc < 2; ++kc) {                                    \
                bf16x8 bv = *(const bf16x8*)&Vts[nt * 16 + lm][kc * 32 + lq * 8]; \
                o[nt] = __builtin_amdgcn_mfma_f32_16x16x32_bf16(ap[kc], bv, o[nt], 0, 0, 0); \
            }                                                                   \
        }                                                                       \
    }                                                                           \
} while (0)

#define ATTN_EPI(q0t, l_p, o) do {                                              \
    _Pragma("unroll")                                                           \
    for (int r = 0; r < 4; ++r) {                                               \
        float l = l_p[r];                                                       \
        _Pragma("unroll")                                                       \
        for (int off = 1; off < 16; off <<= 1) l += __shfl_xor(l, off);         \
        const float inv = 1.0f / l;                                             \
        const int qg = (q0t) + w * 16 + lq * 4 + r;                             \
        _Pragma("unroll")                                                       \
        for (int nt = 0; nt < 4; ++nt)                                          \
            Yb[(size_t)qg * 64 + nt * 16 + lm] = f2bf(o[nt][r] * inv);          \
    }                                                                           \
} while (0)

__global__ __launch_bounds__(256) void attn_mfma(
    const unsigned short* __restrict__ Q, const unsigned short* __restrict__ K,
    const unsigned short* __restrict__ Vt, unsigned short* __restrict__ Y)
{
    const int pi = blockIdx.x;        // 0..7 -> 64-query tiles (pi, 15-pi)
    const int bh = blockIdx.y;        // 0..95
    const int qtA = pi, qtB = 15 - pi;
    const int q0A = qtA * 64, q0B = qtB * 64;
    const int tid = threadIdx.x;
    const int lane = tid & 63;
    const int w = tid >> 6;
    const int lm = lane & 15;
    const int lq = lane >> 4;

    __shared__ __align__(16) unsigned short Ks[64][72];
    __shared__ __align__(16) unsigned short Vts[64][72];   // [d][key]
    __shared__ __align__(16) unsigned short Ps[4][16][72];

    const unsigned short* Qb = Q + (size_t)bh * TDIM * 64;
    const unsigned short* Kb = K + (size_t)bh * TDIM * 64;
    const unsigned short* Vtb = Vt + (size_t)bh * 64 * TDIM;
    unsigned short* Yb = Y + (size_t)bh * TDIM * 64;

    bf16x8 aqA[2], aqB[2];
#pragma unroll
    for (int kc = 0; kc < 2; ++kc) {
        aqA[kc] = *(const bf16x8*)&Qb[(size_t)(q0A + w * 16 + lm) * 64 + kc * 32 + lq * 8];
        aqB[kc] = *(const bf16x8*)&Qb[(size_t)(q0B + w * 16 + lm) * 64 + kc * 32 + lq * 8];
    }

    float lA[4] = {}, lB[4] = {};
    f32x4 oA[4] = {}, oB[4] = {};

    const float SC = 0.125f * 1.44269504f;
    const int nktA = qtA + 1;
    const int nktB = qtB + 1;

    for (int kt = 0; kt < nktB; ++kt) {
        const int kbase = kt * 64;
        __syncthreads();
#pragma unroll
        for (int it = 0; it < 2; ++it) {
            const int idx = tid + it * 256;
            const int r = idx >> 3;
            const int c = idx & 7;
            *(u16x8*)&Ks[r][c * 8] =
                *(const u16x8*)&Kb[(size_t)(kbase + r) * 64 + c * 8];
            *(u16x8*)&Vts[r][c * 8] =
                *(const u16x8*)&Vtb[(size_t)r * TDIM + kbase + c * 8];
        }
        __syncthreads();

        ATTN_TILE(aqB, q0B, qtB, lB, oB);
        if (kt < nktA) ATTN_TILE(aqA, q0A, qtA, lA, oA);
    }

    ATTN_EPI(q0A, lA, oA);
    ATTN_EPI(q0B, lB, oB);
}

// ---------------------------------------------------------------------------
// Kernel 3: proj GEMM (m97 structure, unchanged from R8).
// ---------------------------------------------------------------------------
__global__ __launch_bounds__(256) void proj_mfma(
    const unsigned short* __restrict__ Y, const unsigned short* __restrict__ Wt,
    const float* __restrict__ bias, float* __restrict__ out)
{
    const int n0 = blockIdx.x * 128;
    const int m0 = blockIdx.y * 128;
    const int tid = threadIdx.x;
    const int lane = tid & 63;
    const int w = tid >> 6;
    const int wm = w & 1;
    const int wn = w >> 1;
    const int lm = lane & 15;
    const int lq = lane >> 4;

    __shared__ __align__(16) unsigned short As[128 * 32];
    __shared__ __align__(16) unsigned short Bs[128 * 32];

    f32x4 acc[4][4] = {};

    const int srow = lane >> 2;
    const int schunk = lane & 3;

    for (int k0 = 0; k0 < CDIM; k0 += 32) {
        const int h = k0 >> 6;
        const int inner = k0 & 63;
        __syncthreads();
#pragma unroll
        for (int c = 0; c < 2; ++c) {
            const int rbase = c * 64 + w * 16;
            const int m = m0 + rbase + srow;
            const int bidx = m >> 10;
            const int t = m & 1023;
            async_copy16(&As[rbase * 32],
                         &Y[(((size_t)bidx * 12 + h) * TDIM + t) * 64 + inner + schunk * 8]);
            async_copy16(&Bs[rbase * 32],
                         &Wt[(size_t)(n0 + rbase + srow) * CDIM + k0 + schunk * 8]);
        }
        __syncthreads();

        bf16x8 a[4], b[4];
#pragma unroll
        for (int mi = 0; mi < 4; ++mi)
            a[mi] = *(const bf16x8*)&As[(wm * 64 + mi * 16 + lm) * 32 + lq * 8];
#pragma unroll
        for (int ni = 0; ni < 4; ++ni)
            b[ni] = *(const bf16x8*)&Bs[(wn * 64 + ni * 16 + lm) * 32 + lq * 8];
#pragma unroll
        for (int mi = 0; mi < 4; ++mi)
#pragma unroll
            for (int ni = 0; ni < 4; ++ni)
                acc[mi][ni] = __builtin_amdgcn_mfma_f32_16x16x32_bf16(
                    a[mi], b[ni], acc[mi][ni], 0, 0, 0);
    }

#pragma unroll
    for (int ni = 0; ni < 4; ++ni) {
        const int gn = n0 + wn * 64 + ni * 16 + lm;
        const float bb = bias[gn];
#pragma unroll
        for (int mi = 0; mi < 4; ++mi) {
#pragma unroll
            for (int r = 0; r < 4; ++r) {
                const int gm = m0 + wm * 64 + mi * 16 + lq * 4 + r;
                out[(size_t)gm * CDIM + gn] = acc[mi][ni][r] + bb;
            }
        }
    }
}

extern "C" void kernel_launch(void* const* d_in, const int* in_sizes, int n_in,
                              void* d_out, int out_size, void* d_ws, size_t ws_size,
                              hipStream_t stream) {
    const float* x      = (const float*)d_in[0];
    const float* W_attn = (const float*)d_in[1];
    const float* b_attn = (const float*)d_in[2];
    const float* W_proj = (const float*)d_in[3];
    const float* b_proj = (const float*)d_in[4];
    float* out = (float*)d_out;

    const size_t per = (size_t)8 * 12 * 1024 * 64;
    unsigned short* Q   = (unsigned short*)d_ws;
    unsigned short* K   = Q + per;
    unsigned short* Vt  = K + per;   // [B,H,D,T] transposed
    unsigned short* xb  = Vt + per;
    unsigned short* Wta = xb + (size_t)8192 * CDIM;
    unsigned short* Wtp = Wta + (size_t)NDIM * CDIM;

    cast_x<<<dim3(6144), 256, 0, stream>>>(x, xb);
    transpose_cast<NDIM><<<dim3(72, 24), 256, 0, stream>>>(W_attn, Wta);
    transpose_cast<CDIM><<<dim3(24, 24), 256, 0, stream>>>(W_proj, Wtp);

    qkv_mfma<<<dim3(288), 512, 0, stream>>>(xb, Wta, b_attn, Q, K, Vt);
    attn_mfma<<<dim3(8, 96), 256, 0, stream>>>(Q, K, Vt, Q);
    proj_mfma<<<dim3(6, 64), 256, 0, stream>>>(Q, Wtp, b_proj, out);
}

// Round 2
// 187.364 us; speedup vs baseline: 1.0881x; 1.0445x over previous
//
#include <hip/hip_runtime.h>
#include <hip/hip_bf16.h>

// Problem: B=8, T=1024, C=768, H=12, HD=64. M = 8192. fp32 in/out.
// R15: qkv GEMM restructured for co-residency. 128x256 tile, 8 waves (2Mx4N),
// BK=32, 3-buffer LDS (72KB) with depth-2 prefetch + counted vmcnt(3),
// <=128 VGPR (launch_bounds(512,4)) -> 2 blocks/CU, grid 576 all-resident in
// ~1.15 rounds (vs R14's 256^2 @ 1 block/CU = 2.0 rounds). BK=32 swizzle:
// chunk' = c ^ ((row>>1)&3) (64B rows, 128B bank period), applied to
// pre-swizzled global source + ds_read (both-sides). Epilogue logic = R13/R14
// (per-wave 64-col group, ga = bx*4+wn). attn (R12) + proj + casts unchanged.

#define TDIM 1024
#define CDIM 768
#define NDIM 2304

typedef __attribute__((ext_vector_type(8))) short bf16x8;
typedef __attribute__((ext_vector_type(8))) unsigned short u16x8;
typedef __attribute__((ext_vector_type(4))) float f32x4;

__device__ __forceinline__ unsigned short f2bf(float f) {
    unsigned int u;
    __builtin_memcpy(&u, &f, 4);
    u += 0x7FFFu + ((u >> 16) & 1u);  // RNE
    return (unsigned short)(u >> 16);
}

__device__ __forceinline__ void async_copy16(void* lds, const void* g) {
    __builtin_amdgcn_global_load_lds(
        (const __attribute__((address_space(1))) void*)g,
        (__attribute__((address_space(3))) void*)lds, 16, 0, 0);
}

// ---------------------------------------------------------------------------
// Precast kernels.
// ---------------------------------------------------------------------------
__global__ __launch_bounds__(256) void cast_x(const float* __restrict__ x,
                                              unsigned short* __restrict__ xb) {
    const size_t i = ((size_t)blockIdx.x * 256 + threadIdx.x) * 4;
    float4 v = *(const float4*)&x[i];
    ushort4 s;
    s.x = f2bf(v.x); s.y = f2bf(v.y); s.z = f2bf(v.z); s.w = f2bf(v.w);
    *(ushort4*)&xb[i] = s;
}

template <int N>
__global__ __launch_bounds__(256) void transpose_cast(const float* __restrict__ W,
                                                      unsigned short* __restrict__ Wt) {
    __shared__ float tile[32][33];
    const int n0 = blockIdx.x * 32;
    const int k0 = blockIdx.y * 32;
    const int tx = threadIdx.x & 31;
    const int ty = threadIdx.x >> 5;
#pragma unroll
    for (int i = 0; i < 4; ++i)
        tile[ty + i * 8][tx] = W[(size_t)(k0 + ty + i * 8) * N + n0 + tx];
    __syncthreads();
#pragma unroll
    for (int i = 0; i < 4; ++i)
        Wt[(size_t)(n0 + ty + i * 8) * CDIM + k0 + tx] = f2bf(tile[tx][ty + i * 8]);
}

// ---------------------------------------------------------------------------
// Kernel 1: qkv GEMM — 128(M) x 256(N) tile, BK=32, 8 waves (2M x 4N),
// 3-buffer LDS, depth-2 prefetch, vmcnt(3) per tile, 2 blocks/CU.
//
// LDS buf p in {0,1,2} at p*24KB: A = 128 rows x 64B (8KB), B at +8KB =
// 256 rows x 64B (16KB). Identity row mapping; chunk (16B unit) swizzle
// c' = c ^ ((row>>1)&3), pre-applied to the GLOBAL source (linear LDS dest,
// per global_load_lds constraint) and matched on ds_read.
// Per tile: A stage = 1 load/thread, B = 2 -> 3 loads/thread/tile.
// Steady state: during tile t stage tile t+2 -> outstanding 6 at tile end,
// vmcnt(3) waits for tile t+1's 3 (2-tile latency window).
// ---------------------------------------------------------------------------
__global__ __launch_bounds__(512, 4) void qkv_mfma(
    const unsigned short* __restrict__ xb, const unsigned short* __restrict__ Wt,
    const float* __restrict__ bias,
    unsigned short* __restrict__ Q, unsigned short* __restrict__ Kd,
    unsigned short* __restrict__ Vt)
{
    // XCD-aware swizzle: 576 blocks, 576 % 8 == 0 -> bijective. 72 blocks/XCD
    // = 8 M-strips x 9 N-tiles (A-panel reuse within XCD L2).
    const int wg = ((int)blockIdx.x & 7) * 72 + ((int)blockIdx.x >> 3);
    const int bx = wg % 9;
    const int by = wg / 9;
    const int n0 = bx * 256;
    const int m0 = by * 128;
    const int tid = threadIdx.x;
    const int lane = tid & 63;
    const int w = tid >> 6;
    const int wm = w >> 2;   // 0..1
    const int wn = w & 3;    // 0..3
    const int lm = lane & 15;
    const int lq = lane >> 4;

    __shared__ __align__(16) unsigned short lds[36864];  // 72 KiB (3 x 24KB)

    // Bias preloaded before staging: these vmem loads drain inside the
    // prologue vmcnt and don't perturb the in-loop vmcnt(3) accounting.
    float bb[4];
#pragma unroll
    for (int ni = 0; ni < 4; ++ni) bb[ni] = bias[n0 + wn * 64 + ni * 16 + lm];

    f32x4 acc[4][4] = {};

    // ds_read swizzled chunk: eo = lq ^ ((lm>>1)&3)  (row bits 1..2 == lm bits
    // 1..2 since frag row bases are multiples of 16).
    const int eo = lq ^ ((lm >> 1) & 3);
    // Per-thread constant LDS read offsets (ushort units; row stride 32).
    int aoffc[4], boffc[4];
#pragma unroll
    for (int mi = 0; mi < 4; ++mi)
        aoffc[mi] = (wm * 64 + mi * 16 + lm) * 32 + eo * 8;
#pragma unroll
    for (int ni = 0; ni < 4; ++ni)
        boffc[ni] = 4096 + (wn * 64 + ni * 16 + lm) * 32 + eo * 8;

    // Per-thread constant staging source indices (elements).
    const int rowA = tid >> 2;
    const int ccA = (tid & 3) ^ ((rowA >> 1) & 3);
    const int srcA = rowA * CDIM + ccA * 8;          // + m0*CDIM + kt*32
    int srcB[2];
#pragma unroll
    for (int j = 0; j < 2; ++j) {
        const int lin = j * 512 + tid;
        const int rowB = lin >> 2;
        const int ccB = (lin & 3) ^ ((rowB >> 1) & 3);
        srcB[j] = rowB * CDIM + ccB * 8;             // + n0*CDIM + kt*32
    }
    const unsigned short* xbb = xb + (size_t)m0 * CDIM;
    const unsigned short* Wtb = Wt + (size_t)n0 * CDIM;

#define STAGE(p, kt)                                                            \
    do {                                                                        \
        async_copy16(&lds[(p) * 12288 + w * 512], &xbb[srcA + (kt) * 32]);      \
        _Pragma("unroll")                                                       \
        for (int j = 0; j < 2; ++j)                                             \
            async_copy16(&lds[(p) * 12288 + 4096 + j * 4096 + w * 512],         \
                         &Wtb[srcB[j] + (kt) * 32]);                            \
    } while (0)

#define TILE(p, ktn)                                                            \
    do {                                                                        \
        STAGE((p + 2) % 3, ktn);                                                \
        bf16x8 a[4], b[4];                                                      \
        _Pragma("unroll")                                                       \
        for (int mi = 0; mi < 4; ++mi)                                          \
            a[mi] = *(const bf16x8*)&lds[(p) * 12288 + aoffc[mi]];              \
        _Pragma("unroll")                                                       \
        for (int ni = 0; ni < 4; ++ni)                                          \
            b[ni] = *(const bf16x8*)&lds[(p) * 12288 + boffc[ni]];              \
        __builtin_amdgcn_s_setprio(1);                                          \
        _Pragma("unroll")                                                       \
        for (int mi = 0; mi < 4; ++mi)                                          \
            _Pragma("unroll")                                                   \
            for (int ni = 0; ni < 4; ++ni)                                      \
                acc[mi][ni] = __builtin_amdgcn_mfma_f32_16x16x32_bf16(          \
                    a[mi], b[ni], acc[mi][ni], 0, 0, 0);                        \
        __builtin_amdgcn_s_setprio(0);                                          \
        asm volatile("s_waitcnt vmcnt(3)" ::: "memory");                        \
        __builtin_amdgcn_s_barrier();                                           \
    } while (0)

    // Prologue: stage tiles 0,1 (buf0,buf1); wait tile0 (vmcnt(3) leaves
    // tile1's 3 in flight, drains bias + tile0).
    STAGE(0, 0);
    STAGE(1, 1);
    asm volatile("s_waitcnt vmcnt(3)" ::: "memory");
    __builtin_amdgcn_s_barrier();

#pragma unroll 1
    for (int it = 0; it < 8; ++it) {
        const int k2 = (3 * it + 2 < 24) ? 3 * it + 2 : 23;
        const int k3 = (3 * it + 3 < 24) ? 3 * it + 3 : 23;  // clamp: dead
        const int k4 = (3 * it + 4 < 24) ? 3 * it + 4 : 23;  // restage benign
        TILE(0, k2);
        TILE(1, k3);
        TILE(2, k4);
    }

#undef STAGE
#undef TILE

    // Drain all outstanding DMA before reusing LDS as epilogue scratch.
    asm volatile("s_waitcnt vmcnt(0)" ::: "memory");
    __builtin_amdgcn_s_barrier();

    // Epilogue. Wave's 64-col group: ga = bx*4 + wn; which = ga%3; h = ga/3.
    const int ga = bx * 4 + wn;
    const int which = ga % 3;
    const int h = ga / 3;

    if (which == 2) {
        // V transposed [B,H,D,T]: direct t-contiguous ushort4 stores.
#pragma unroll
        for (int ni = 0; ni < 4; ++ni) {
            const int d = ni * 16 + lm;
#pragma unroll
            for (int mi = 0; mi < 4; ++mi) {
                const int gm0 = m0 + wm * 64 + mi * 16 + lq * 4;
                const int bidx = gm0 >> 10;
                const int t0 = gm0 & 1023;
                ushort4 sv;
                sv.x = f2bf(acc[mi][ni][0] + bb[ni]);
                sv.y = f2bf(acc[mi][ni][1] + bb[ni]);
                sv.z = f2bf(acc[mi][ni][2] + bb[ni]);
                sv.w = f2bf(acc[mi][ni][3] + bb[ni]);
                *(ushort4*)&Vt[(((size_t)bidx * 12 + h) * 64 + d) * TDIM + t0] = sv;
            }
        }
    } else {
        // Q/K [B,H,T,64]: per-wave LDS transpose -> 16B row stores.
        unsigned short* dst = (which == 0) ? Q : Kd;
        unsigned short* Es = &lds[w * 1152];  // 16 x 72 per wave
        const int erow = lane >> 2;   // 0..15
        const int ecol = lane & 3;    // 0..3 -> 16-short chunks
#pragma unroll
        for (int mi = 0; mi < 4; ++mi) {
#pragma unroll
            for (int r = 0; r < 4; ++r)
#pragma unroll
                for (int ni = 0; ni < 4; ++ni)
                    Es[(lq * 4 + r) * 72 + ni * 16 + lm] = f2bf(acc[mi][ni][r] + bb[ni]);
            // same-wave LDS write->read (in-order per wave; validated since R7)
            const int t = m0 + wm * 64 + mi * 16 + erow;
            const int bidx = t >> 10;
            const int tt = t & 1023;
            unsigned short* drow = &dst[(((size_t)bidx * 12 + h) * TDIM + tt) * 64];
            u16x8 v0 = *(const u16x8*)&Es[erow * 72 + ecol * 16];
            u16x8 v1 = *(const u16x8*)&Es[erow * 72 + ecol * 16 + 8];
            *(u16x8*)&drow[ecol * 16] = v0;
            *(u16x8*)&drow[ecol * 16 + 8] = v1;
        }
    }
}

// ---------------------------------------------------------------------------
// Kernel 2: MFMA causal flash attention v4 (R12, verified) — 64-query tiles
// paired (pi, 15-pi); shift-free softmax; V pre-transposed; Q frags direct.
// ---------------------------------------------------------------------------
#define ATTN_TILE(aq, q0t, qt_t, l_p, o) do {                                   \
    const bool diag_ = (kt == (qt_t));                                          \
    float pf[4][4];                                                             \
    _Pragma("unroll")                                                           \
    for (int nt = 0; nt < 4; ++nt) {                                            \
        f32x4 s = {};                                                           \
        _Pragma("unroll")                                                       \
        for (int kc = 0; kc < 2; ++kc) {                                        \
            bf16x8 bfrag = *(const bf16x8*)&Ks[nt * 16 + lm][kc * 32 + lq * 8]; \
            s = __builtin_amdgcn_mfma_f32_16x16x32_bf16(aq[kc], bfrag, s, 0, 0, 0); \
        }                                                                       \
        const int keyg = kbase + nt * 16 + lm;                                  \
        _Pragma("unroll")                                                       \
        for (int r = 0; r < 4; ++r) {                                           \
            float p = __builtin_amdgcn_exp2f(s[r] * SC);                        \
            if (diag_) {                                                        \
                const int qg = (q0t) + w * 16 + lq * 4 + r;                     \
                if (keyg > qg) p = 0.f;                                         \
            }                                                                   \
            pf[nt][r] = p;                                                      \
        }                                                                       \
    }                                                                           \
    _Pragma("unroll")                                                           \
    for (int r = 0; r < 4; ++r) {                                               \
        l_p[r] += pf[0][r] + pf[1][r] + pf[2][r] + pf[3][r];                    \
        _Pragma("unroll")                                                       \
        for (int nt = 0; nt < 4; ++nt)                                          \
            Ps[w][lq * 4 + r][nt * 16 + lm] = f2bf(pf[nt][r]);                  \
    }                                                                           \
    {                                                                           \
        bf16x8 ap[2];                                                           \
        _Pragma("unroll")                                                       \
        for (int kc = 0; kc < 2; ++kc)                                          \
            ap[kc] = *(const bf16x8*)&Ps[w][lm][kc * 32 + lq * 8];              \
        _Pragma("unroll")                                                       \
        for (int nt = 0; nt < 4; ++nt) {                                        \
            _Pragma("unroll")                                                   \
            for (int kc = 0; kc < 2; ++kc) {                                    \
                bf16x8 bv = *(const bf16x8*)&Vts[nt * 16 + lm][kc * 32 + lq * 8]; \
                o[nt] = __builtin_amdgcn_mfma_f32_16x16x32_bf16(ap[kc], bv, o[nt], 0, 0, 0); \
            }                                                                   \
        }                                                                       \
    }                                                                           \
} while (0)

#define ATTN_EPI(q0t, l_p, o) do {                                              \
    _Pragma("unroll")                                                           \
    for (int r = 0; r < 4; ++r) {                                               \
        float l = l_p[r];                                                       \
        _Pragma("unroll")                                                       \
        for (int off = 1; off < 16; off <<= 1) l += __shfl_xor(l, off);         \
        const float inv = 1.0f / l;                                             \
        const int qg = (q0t) + w * 16 + lq * 4 + r;                             \
        _Pragma("unroll")                                                       \
        for (int nt = 0; nt < 4; ++nt)                                          \
            Yb[(size_t)qg * 64 + nt * 16 + lm] = f2bf(o[nt][r] * inv);          \
    }                                                                           \
} while (0)

__global__ __launch_bounds__(256) void attn_mfma(
    const unsigned short* __restrict__ Q, const unsigned short* __restrict__ K,
    const unsigned short* __restrict__ Vt, unsigned short* __restrict__ Y)
{
    const int pi = blockIdx.x;        // 0..7 -> 64-query tiles (pi, 15-pi)
    const int bh = blockIdx.y;        // 0..95
    const int qtA = pi, qtB = 15 - pi;
    const int q0A = qtA * 64, q0B = qtB * 64;
    const int tid = threadIdx.x;
    const int lane = tid & 63;
    const int w = tid >> 6;
    const int lm = lane & 15;
    const int lq = lane >> 4;

    __shared__ __align__(16) unsigned short Ks[64][72];
    __shared__ __align__(16) unsigned short Vts[64][72];   // [d][key]
    __shared__ __align__(16) unsigned short Ps[4][16][72];

    const unsigned short* Qb = Q + (size_t)bh * TDIM * 64;
    const unsigned short* Kb = K + (size_t)bh * TDIM * 64;
    const unsigned short* Vtb = Vt + (size_t)bh * 64 * TDIM;
    unsigned short* Yb = Y + (size_t)bh * TDIM * 64;

    bf16x8 aqA[2], aqB[2];
#pragma unroll
    for (int kc = 0; kc < 2; ++kc) {
        aqA[kc] = *(const bf16x8*)&Qb[(size_t)(q0A + w * 16 + lm) * 64 + kc * 32 + lq * 8];
        aqB[kc] = *(const bf16x8*)&Qb[(size_t)(q0B + w * 16 + lm) * 64 + kc * 32 + lq * 8];
    }

    float lA[4] = {}, lB[4] = {};
    f32x4 oA[4] = {}, oB[4] = {};

    const float SC = 0.125f * 1.44269504f;
    const int nktA = qtA + 1;
    const int nktB = qtB + 1;

    for (int kt = 0; kt < nktB; ++kt) {
        const int kbase = kt * 64;
        __syncthreads();
#pragma unroll
        for (int it = 0; it < 2; ++it) {
            const int idx = tid + it * 256;
            const int r = idx >> 3;
            const int c = idx & 7;
            *(u16x8*)&Ks[r][c * 8] =
                *(const u16x8*)&Kb[(size_t)(kbase + r) * 64 + c * 8];
            *(u16x8*)&Vts[r][c * 8] =
                *(const u16x8*)&Vtb[(size_t)r * TDIM + kbase + c * 8];
        }
        __syncthreads();

        ATTN_TILE(aqB, q0B, qtB, lB, oB);
        if (kt < nktA) ATTN_TILE(aqA, q0A, qtA, lA, oA);
    }

    ATTN_EPI(q0A, lA, oA);
    ATTN_EPI(q0B, lB, oB);
}

// ---------------------------------------------------------------------------
// Kernel 3: proj GEMM (m97 structure, unchanged from R8).
// ---------------------------------------------------------------------------
__global__ __launch_bounds__(256) void proj_mfma(
    const unsigned short* __restrict__ Y, const unsigned short* __restrict__ Wt,
    const float* __restrict__ bias, float* __restrict__ out)
{
    const int n0 = blockIdx.x * 128;
    const int m0 = blockIdx.y * 128;
    const int tid = threadIdx.x;
    const int lane = tid & 63;
    const int w = tid >> 6;
    const int wm = w & 1;
    const int wn = w >> 1;
    const int lm = lane & 15;
    const int lq = lane >> 4;

    __shared__ __align__(16) unsigned short As[128 * 32];
    __shared__ __align__(16) unsigned short Bs[128 * 32];

    f32x4 acc[4][4] = {};

    const int srow = lane >> 2;
    const int schunk = lane & 3;

    for (int k0 = 0; k0 < CDIM; k0 += 32) {
        const int h = k0 >> 6;
        const int inner = k0 & 63;
        __syncthreads();
#pragma unroll
        for (int c = 0; c < 2; ++c) {
            const int rbase = c * 64 + w * 16;
            const int m = m0 + rbase + srow;
            const int bidx = m >> 10;
            const int t = m & 1023;
            async_copy16(&As[rbase * 32],
                         &Y[(((size_t)bidx * 12 + h) * TDIM + t) * 64 + inner + schunk * 8]);
            async_copy16(&Bs[rbase * 32],
                         &Wt[(size_t)(n0 + rbase + srow) * CDIM + k0 + schunk * 8]);
        }
        __syncthreads();

        bf16x8 a[4], b[4];
#pragma unroll
        for (int mi = 0; mi < 4; ++mi)
            a[mi] = *(const bf16x8*)&As[(wm * 64 + mi * 16 + lm) * 32 + lq * 8];
#pragma unroll
        for (int ni = 0; ni < 4; ++ni)
            b[ni] = *(const bf16x8*)&Bs[(wn * 64 + ni * 16 + lm) * 32 + lq * 8];
#pragma unroll
        for (int mi = 0; mi < 4; ++mi)
#pragma unroll
            for (int ni = 0; ni < 4; ++ni)
                acc[mi][ni] = __builtin_amdgcn_mfma_f32_16x16x32_bf16(
                    a[mi], b[ni], acc[mi][ni], 0, 0, 0);
    }

#pragma unroll
    for (int ni = 0; ni < 4; ++ni) {
        const int gn = n0 + wn * 64 + ni * 16 + lm;
        const float bb = bias[gn];
#pragma unroll
        for (int mi = 0; mi < 4; ++mi) {
#pragma unroll
            for (int r = 0; r < 4; ++r) {
                const int gm = m0 + wm * 64 + mi * 16 + lq * 4 + r;
                out[(size_t)gm * CDIM + gn] = acc[mi][ni][r] + bb;
            }
        }
    }
}

extern "C" void kernel_launch(void* const* d_in, const int* in_sizes, int n_in,
                              void* d_out, int out_size, void* d_ws, size_t ws_size,
                              hipStream_t stream) {
    const float* x      = (const float*)d_in[0];
    const float* W_attn = (const float*)d_in[1];
    const float* b_attn = (const float*)d_in[2];
    const float* W_proj = (const float*)d_in[3];
    const float* b_proj = (const float*)d_in[4];
    float* out = (float*)d_out;

    const size_t per = (size_t)8 * 12 * 1024 * 64;
    unsigned short* Q   = (unsigned short*)d_ws;
    unsigned short* K   = Q + per;
    unsigned short* Vt  = K + per;   // [B,H,D,T] transposed
    unsigned short* xb  = Vt + per;
    unsigned short* Wta = xb + (size_t)8192 * CDIM;
    unsigned short* Wtp = Wta + (size_t)NDIM * CDIM;

    cast_x<<<dim3(6144), 256, 0, stream>>>(x, xb);
    transpose_cast<NDIM><<<dim3(72, 24), 256, 0, stream>>>(W_attn, Wta);
    transpose_cast<CDIM><<<dim3(24, 24), 256, 0, stream>>>(W_proj, Wtp);

    qkv_mfma<<<dim3(576), 512, 0, stream>>>(xb, Wta, b_attn, Q, K, Vt);
    attn_mfma<<<dim3(8, 96), 256, 0, stream>>>(Q, K, Vt, Q);
    proj_mfma<<<dim3(6, 64), 256, 0, stream>>>(Q, Wtp, b_proj, out);
}